// Round 16
// baseline (677.072 us; speedup 1.0000x reference)
//
#include <hip/hip_runtime.h>
#include <math.h>

#define N_NODES 200000
#define N_HE    100000
#define NNZ     1000000
#define F_RAW   29
#define N_MACRO 512
#define SLOPE   0.1f
#define L_TOTAL (N_NODES + N_HE)   // 300000 combined counters
#define NB_SCAN 293                // ceil(300000/1024)

typedef __attribute__((ext_vector_type(8))) short bf16x8;
typedef __attribute__((ext_vector_type(4))) float f32x4;

__device__ __forceinline__ float lrelu(float v) { return v >= 0.f ? v : SLOPE * v; }
__device__ __forceinline__ float bf2f(unsigned short u) { return __uint_as_float(((unsigned)u) << 16); }
__device__ __forceinline__ unsigned short f2bf(float f) {
    unsigned u = __float_as_uint(f);
    unsigned r = u + 0x7FFFu + ((u >> 16) & 1u);   // RNE
    return (unsigned short)(r >> 16);
}
__device__ __forceinline__ float bflo(unsigned u) { return __uint_as_float(u << 16); }
__device__ __forceinline__ float bfhi(unsigned u) { return __uint_as_float(u & 0xffff0000u); }

// ---------- fill ----------
__global__ __launch_bounds__(256) void fill_f32(float* p, long long n, float v) {
    long long i = (long long)blockIdx.x * blockDim.x + threadIdx.x;
    long long st = (long long)gridDim.x * blockDim.x;
    for (; i < n; i += st) p[i] = v;
}

// ---------- tiny pre: va (blk 0) + ismacro/mcount (blks 1-2) + Wt transpose (blks 3-10) ----------
__global__ __launch_bounds__(256) void k_tiny(
    const int* __restrict__ mi, float* __restrict__ ismacro, int* __restrict__ mcount,
    const float* __restrict__ W1, const float* __restrict__ b1,
    const float* __restrict__ att, float* __restrict__ va,
    const float* __restrict__ Wpost, unsigned short* __restrict__ Wt)
{
    if (blockIdx.x == 0) {
        int t = threadIdx.x;
        if (t < 32) {
            float a = 0.f;
            for (int c = 0; c < 64; c++) a += W1[t * 64 + c] * att[c];
            va[t] = a;
        } else if (t == 32) {
            float a = 0.f;
            for (int c = 0; c < 64; c++) a += b1[c] * att[c];
            va[32] = a;
        }
    } else if (blockIdx.x <= 2) {
        int i = (blockIdx.x - 1) * 256 + threadIdx.x;
        if (i < N_MACRO) {
            ismacro[mi[i]] = 1.0f;
            atomicAdd(&mcount[mi[i]], 1);
        }
    } else {
        // Wt[c][k] = bf16(Wpost[k][c]), 64x256
        int i = (blockIdx.x - 3) * 256 + threadIdx.x;
        for (int e = i; e < 64 * 256; e += 8 * 256) {
            int c = e >> 8, k = e & 255;
            Wt[c * 256 + k] = f2bf(Wpost[k * 64 + c]);
        }
    }
}

// ---------- count+rank (blocks 0..2047, atomic-bound) || h build (blocks 2048..3071) ----------
__global__ __launch_bounds__(256) void k_cnt_h(
    const int* __restrict__ nidx, const int* __restrict__ hidx,
    int* __restrict__ cnt, int* __restrict__ rank_n, int* __restrict__ rank_e,
    const float* __restrict__ x, const float* __restrict__ fp,
    const float* __restrict__ ismacro, const float* __restrict__ va,
    unsigned short* __restrict__ h, float* __restrict__ xn_att)
{
    if (blockIdx.x < 2048) {
        int i = blockIdx.x * 256 + threadIdx.x;
        int st = 2048 * 256;
        for (int p = i; p < NNZ; p += st) {
            rank_n[p] = atomicAdd(&cnt[nidx[p]], 1);
            rank_e[p] = atomicAdd(&cnt[N_NODES + hidx[p]], 1);
        }
    } else {
        const int lane = threadIdx.x & 63;
        const int half = lane >> 5, k = lane & 31;
        int wid = ((blockIdx.x - 2048) * 256 + threadIdx.x) >> 6;
        int nw = (1024 * 256) >> 6;
        float vak = va[k];
        float c0 = va[32];
        for (int base = wid * 2; base < N_NODES; base += nw * 2) {
            int n = base + half;
            float v;
            if (k < 29)       v = x[(size_t)n * F_RAW + k];
            else if (k == 29) v = fp[2 * n];
            else if (k == 30) v = fp[2 * n + 1];
            else              v = ismacro[n];
            h[(size_t)n * 32 + k] = f2bf(v);
            float r = v * vak;
            #pragma unroll
            for (int o = 16; o > 0; o >>= 1) r += __shfl_xor(r, o, 32);
            if (k == 0) xn_att[n] = r + c0;
        }
    }
}

// ---------- scan of cnt (length L_TOTAL) -> row_ptr ----------
__global__ __launch_bounds__(256) void k_scan1(const int* __restrict__ cnt,
                                               int* __restrict__ row_ptr, int* __restrict__ partials)
{
    __shared__ int sA[256], sB[256];
    const int t = threadIdx.x;
    const int base = blockIdx.x * 1024 + t * 4;
    int v0 = base + 0 < L_TOTAL ? cnt[base + 0] : 0;
    int v1 = base + 1 < L_TOTAL ? cnt[base + 1] : 0;
    int v2 = base + 2 < L_TOTAL ? cnt[base + 2] : 0;
    int v3 = base + 3 < L_TOTAL ? cnt[base + 3] : 0;
    sA[t] = v0 + v1 + v2 + v3;
    __syncthreads();
    int* src = sA; int* dst = sB;
    for (int off = 1; off < 256; off <<= 1) {
        int v = src[t];
        if (t >= off) v += src[t - off];
        dst[t] = v;
        __syncthreads();
        int* tmp = src; src = dst; dst = tmp;
    }
    int excl = t > 0 ? src[t - 1] : 0;
    if (base + 0 < L_TOTAL) row_ptr[base + 0] = excl;
    if (base + 1 < L_TOTAL) row_ptr[base + 1] = excl + v0;
    if (base + 2 < L_TOTAL) row_ptr[base + 2] = excl + v0 + v1;
    if (base + 3 < L_TOTAL) row_ptr[base + 3] = excl + v0 + v1 + v2;
    if (t == 255) partials[blockIdx.x] = src[255];
}

__global__ __launch_bounds__(512) void k_scan2(int* __restrict__ partials)
{
    __shared__ int sA[512], sB[512];
    const int t = threadIdx.x;
    sA[t] = t < NB_SCAN ? partials[t] : 0;
    __syncthreads();
    int* src = sA; int* dst = sB;
    for (int off = 1; off < 512; off <<= 1) {
        int v = src[t];
        if (t >= off) v += src[t - off];
        dst[t] = v;
        __syncthreads();
        int* tmp = src; src = dst; dst = tmp;
    }
    if (t < NB_SCAN) partials[t] = t > 0 ? src[t - 1] : 0;
    if (t == 0) partials[NB_SCAN] = src[511];
}

__global__ __launch_bounds__(256) void k_scan3(int* __restrict__ row_ptr, const int* __restrict__ partials)
{
    const int base = blockIdx.x * 1024 + threadIdx.x * 4;
    int add = partials[blockIdx.x];
    #pragma unroll
    for (int k = 0; k < 4; k++)
        if (base + k < L_TOTAL) row_ptr[base + k] += add;
    if (blockIdx.x == 0 && threadIdx.x == 0) row_ptr[L_TOTAL] = partials[NB_SCAN];
}

// ---------- scatter: node-side he ids + he-side int4 record {node, pf01, pf23, 0} ----------
__global__ __launch_bounds__(256) void k_scatter(
    const int* __restrict__ nidx, const int* __restrict__ hidx,
    const int* __restrict__ row_ptr,
    const int* __restrict__ rank_n, const int* __restrict__ rank_e,
    const float4* __restrict__ pf4, int* __restrict__ csr_n, int4* __restrict__ rec)
{
    int i = blockIdx.x * 256 + threadIdx.x;
    int st = gridDim.x * 256;
    for (int p = i; p < NNZ; p += st) {
        int n = nidx[p], e = hidx[p];
        csr_n[row_ptr[n] + rank_n[p]] = e;
        int pe = row_ptr[N_NODES + e] + rank_e[p];  // absolute he slot (>= NNZ)
        float4 q = pf4[p];
        int4 r;
        r.x = n;
        r.y = (int)((unsigned)f2bf(q.x) | ((unsigned)f2bf(q.y) << 16));
        r.z = (int)((unsigned)f2bf(q.z) | ((unsigned)f2bf(q.w) << 16));
        r.w = 0;
        rec[pe - NNZ] = r;
    }
}

// ---------- he-side: 8-lane pin groups, merged rec reads ----------
__global__ __launch_bounds__(256) void k_he_agg(
    const int* __restrict__ row_ptr, const int4* __restrict__ rec,
    const float* __restrict__ W1, const float* __restrict__ Wpin,
    const float* __restrict__ b1, const float* __restrict__ att,
    const unsigned short* __restrict__ h,
    unsigned short* __restrict__ e_feat, float* __restrict__ e_att)
{
    __shared__ float sW1[32 * 64];
    __shared__ float sWp[4 * 64];
    __shared__ float sb1[64];
    for (int i = threadIdx.x; i < 32 * 64; i += 256) sW1[i] = W1[i];
    for (int i = threadIdx.x; i < 4 * 64; i += 256) sWp[i] = Wpin[i];
    if (threadIdx.x < 64) sb1[threadIdx.x] = b1[threadIdx.x];
    __syncthreads();
    const int lane = threadIdx.x & 63;
    const int g  = lane >> 3;    // pin group 0..7
    const int gl = lane & 7;     // channel quad: k = 4gl..4gl+3
    float att2 = att[64 + lane];
    int wid = (blockIdx.x * blockDim.x + threadIdx.x) >> 6;
    int nw = (gridDim.x * blockDim.x) >> 6;
    for (int e = wid; e < N_HE; e += nw) {
        int start = row_ptr[N_NODES + e];
        int deg = row_ptr[N_NODES + e + 1] - start;
        float h0 = 0.f, h1 = 0.f, h2 = 0.f, h3 = 0.f;
        float pa = 0.f, pb = 0.f;
        const int4* rbase = rec + (start - NNZ);
        int t = g;
        for (; t + 8 < deg; t += 16) {
            int4 rA = rbase[t];
            int4 rB = rbase[t + 8];
            ushort4 uA = *(const ushort4*)&h[(size_t)rA.x * 32 + 4 * gl];
            ushort4 uB = *(const ushort4*)&h[(size_t)rB.x * 32 + 4 * gl];
            h0 += bf2f(uA.x) + bf2f(uB.x);
            h1 += bf2f(uA.y) + bf2f(uB.y);
            h2 += bf2f(uA.z) + bf2f(uB.z);
            h3 += bf2f(uA.w) + bf2f(uB.w);
            unsigned pyA = (gl == 0) ? (unsigned)rA.y : ((gl == 1) ? (unsigned)rA.z : 0u);
            unsigned pyB = (gl == 0) ? (unsigned)rB.y : ((gl == 1) ? (unsigned)rB.z : 0u);
            pa += bflo(pyA) + bflo(pyB);
            pb += bfhi(pyA) + bfhi(pyB);
        }
        if (t < deg) {
            int4 r = rbase[t];
            ushort4 u = *(const ushort4*)&h[(size_t)r.x * 32 + 4 * gl];
            h0 += bf2f(u.x); h1 += bf2f(u.y); h2 += bf2f(u.z); h3 += bf2f(u.w);
            unsigned py = (gl == 0) ? (unsigned)r.y : ((gl == 1) ? (unsigned)r.z : 0u);
            pa += bflo(py); pb += bfhi(py);
        }
        #pragma unroll
        for (int o = 8; o <= 32; o <<= 1) {
            h0 += __shfl_xor(h0, o); h1 += __shfl_xor(h1, o);
            h2 += __shfl_xor(h2, o); h3 += __shfl_xor(h3, o);
            pa += __shfl_xor(pa, o); pb += __shfl_xor(pb, o);
        }
        float p0 = __shfl(pa, 0, 64), p1 = __shfl(pb, 0, 64);
        float p2 = __shfl(pa, 1, 64), p3 = __shfl(pb, 1, 64);
        float acc = (float)deg * sb1[lane]
                  + p0 * sWp[lane] + p1 * sWp[64 + lane]
                  + p2 * sWp[128 + lane] + p3 * sWp[192 + lane];
        #pragma unroll
        for (int kk = 0; kk < 8; kk++) {
            float a0 = __shfl(h0, kk, 64), a1 = __shfl(h1, kk, 64);
            float a2 = __shfl(h2, kk, 64), a3 = __shfl(h3, kk, 64);
            acc += a0 * sW1[(4 * kk + 0) * 64 + lane] + a1 * sW1[(4 * kk + 1) * 64 + lane]
                 + a2 * sW1[(4 * kk + 2) * 64 + lane] + a3 * sW1[(4 * kk + 3) * 64 + lane];
        }
        float d = (float)(deg > 0 ? deg : 1);
        float v = acc / d;
        e_feat[(size_t)e * 64 + lane] = f2bf(v);
        float r = v * att2;
        #pragma unroll
        for (int o = 32; o > 0; o >>= 1) r += __shfl_down(r, o, 64);
        if (lane == 0) e_att[e] = r;
    }
}

// ---------- BARRIER-FREE fused softmax+PNA + MFMA post-GEMM + pools ----------
// Each WAVE owns a 16-node batch in its private LDS region (no __syncthreads
// anywhere). Phase A: R11's half-wave pin split (best measured), 16 nodes/wave.
// Phase B: wave computes all 64 channels in 4 MFMA rounds; B-frag loaded
// per-MFMA from pre-transposed bf16 Wt[c][k] (L1-hot, one 16B load each).
// C-layout per round r: channel = r*16 + (lane&15), node = 4*(lane>>4)+reg.
__global__ __launch_bounds__(256, 4) void k_fused(
    const int* __restrict__ row_ptr, const int* __restrict__ csr,
    const float* __restrict__ xn_att, const float* __restrict__ e_att,
    const unsigned short* __restrict__ e_feat,
    const unsigned short* __restrict__ Wt, const float* __restrict__ bpost,
    const int* __restrict__ mcount,
    float* __restrict__ sum_all, float* __restrict__ sum_mac)
{
    __shared__ __align__(16) unsigned short scat[4][16 * 264];   // 33,792 B (per-wave regions)
    const int lane = threadIdx.x & 63;
    const int wave = threadIdx.x >> 6;
    const int half = lane >> 5;     // pin parity (phase A)
    const int c2   = lane & 31;     // channel pair (phase A)
    const int quad = lane >> 4;     // phase B
    const int nn   = lane & 15;     // phase B
    unsigned short* ws = &scat[wave][0];
    float bias0 = bpost[0 * 16 + nn], bias1 = bpost[1 * 16 + nn];
    float bias2 = bpost[2 * 16 + nn], bias3 = bpost[3 * 16 + nn];
    float pool0 = 0.f, pool1 = 0.f, pool2 = 0.f, pool3 = 0.f;
    float pmac0 = 0.f, pmac1 = 0.f, pmac2 = 0.f, pmac3 = 0.f;
    const int nbatches = N_NODES / 16;  // 12500
    const int wid0 = blockIdx.x * 4 + wave;
    const int nwv = gridDim.x * 4;
    for (int b = wid0; b < nbatches; b += nwv) {
        const int base = b * 16;
        // ---- phase A: 16 nodes sequentially; two 32-lane halves split pins ----
        for (int j = 0; j < 16; j++) {
            int n = base + j;
            int start = row_ptr[n];
            int deg = row_ptr[n + 1] - start;
            float xn = xn_att[n];
            float sw = 0.f;
            float sx = 0.f, sy = 0.f, qx = 0.f, qy = 0.f;
            float mxx = -INFINITY, mxy = -INFINITY, mnx = INFINITY, mny = INFINITY;
            int t = half;
            for (; t + 2 < deg; t += 4) {
                int e0 = csr[start + t];
                int e1 = csr[start + t + 2];
                float w0 = __expf(lrelu(xn + e_att[e0]));
                float w1 = __expf(lrelu(xn + e_att[e1]));
                unsigned u0 = ((const unsigned*)&e_feat[(size_t)e0 * 64])[c2];
                unsigned u1 = ((const unsigned*)&e_feat[(size_t)e1 * 64])[c2];
                float v0x = bflo(u0) * w0, v0y = bfhi(u0) * w0;
                float v1x = bflo(u1) * w1, v1y = bfhi(u1) * w1;
                sw += w0 + w1;
                sx += v0x + v1x; sy += v0y + v1y;
                qx += v0x * v0x + v1x * v1x; qy += v0y * v0y + v1y * v1y;
                mxx = fmaxf(mxx, fmaxf(v0x, v1x)); mxy = fmaxf(mxy, fmaxf(v0y, v1y));
                mnx = fminf(mnx, fminf(v0x, v1x)); mny = fminf(mny, fminf(v0y, v1y));
            }
            for (; t < deg; t += 2) {
                int e = csr[start + t];
                float w = __expf(lrelu(xn + e_att[e]));
                unsigned u = ((const unsigned*)&e_feat[(size_t)e * 64])[c2];
                float vx = bflo(u) * w, vy = bfhi(u) * w;
                sw += w; sx += vx; sy += vy; qx += vx * vx; qy += vy * vy;
                mxx = fmaxf(mxx, vx); mxy = fmaxf(mxy, vy);
                mnx = fminf(mnx, vx); mny = fminf(mny, vy);
            }
            // combine the two halves (exact: sums add, max/min merge)
            sw  += __shfl_xor(sw, 32);
            sx  += __shfl_xor(sx, 32);  sy += __shfl_xor(sy, 32);
            qx  += __shfl_xor(qx, 32);  qy += __shfl_xor(qy, 32);
            mxx = fmaxf(mxx, __shfl_xor(mxx, 32)); mxy = fmaxf(mxy, __shfl_xor(mxy, 32));
            mnx = fminf(mnx, __shfl_xor(mnx, 32)); mny = fminf(mny, __shfl_xor(mny, 32));
            float invD = 1.f / (sw + 1e-16f);
            float dc = (float)(deg > 0 ? deg : 1);
            float meanx = sx * invD / dc, meany = sy * invD / dc;
            float sqmx = qx * invD * invD / dc, sqmy = qy * invD * invD / dc;
            float stdx = sqrtf(fmaxf(sqmx - meanx * meanx, 0.f) + 1e-12f);
            float stdy = sqrtf(fmaxf(sqmy - meany * meany, 0.f) + 1e-12f);
            ushort2* row = (ushort2*)&ws[j * 264];
            if (half == 0) {
                ushort2 a; a.x = f2bf(meanx); a.y = f2bf(meany);
                row[c2] = a;
                ushort2 bmax; bmax.x = f2bf(deg > 0 ? mxx * invD : 0.f);
                bmax.y = f2bf(deg > 0 ? mxy * invD : 0.f);
                row[32 + c2] = bmax;
            } else {
                ushort2 bmin; bmin.x = f2bf(deg > 0 ? mnx * invD : 0.f);
                bmin.y = f2bf(deg > 0 ? mny * invD : 0.f);
                row[64 + c2] = bmin;
                ushort2 bstd; bstd.x = f2bf(stdx); bstd.y = f2bf(stdy);
                row[96 + c2] = bstd;
            }
        }
        // ---- phase B: 4 rounds x 8 MFMAs; A from own LDS region, B from Wt ----
        int4 mc4 = *(const int4*)&mcount[base + 4 * quad];
        #pragma unroll
        for (int r = 0; r < 4; r++) {
            f32x4 acc = {0.f, 0.f, 0.f, 0.f};
            #pragma unroll
            for (int s = 0; s < 8; s++) {
                bf16x8 a = *(const bf16x8*)&ws[nn * 264 + 32 * s + quad * 8];
                bf16x8 bw = *(const bf16x8*)&Wt[(size_t)(r * 16 + nn) * 256 + 32 * s + quad * 8];
                acc = __builtin_amdgcn_mfma_f32_16x16x32_bf16(a, bw, acc, 0, 0, 0);
            }
            float bias = r == 0 ? bias0 : (r == 1 ? bias1 : (r == 2 ? bias2 : bias3));
            float h0 = lrelu(acc[0] + bias);
            float h1 = lrelu(acc[1] + bias);
            float h2 = lrelu(acc[2] + bias);
            float h3 = lrelu(acc[3] + bias);
            float ps = h0 + h1 + h2 + h3;
            float pm = (float)mc4.x * h0 + (float)mc4.y * h1
                     + (float)mc4.z * h2 + (float)mc4.w * h3;
            if (r == 0) { pool0 += ps; pmac0 += pm; }
            else if (r == 1) { pool1 += ps; pmac1 += pm; }
            else if (r == 2) { pool2 += ps; pmac2 += pm; }
            else { pool3 += ps; pmac3 += pm; }
        }
    }
    // reduce across the 4 quad-groups (same channel), one atomic per (round, channel)
    #pragma unroll
    for (int r = 0; r < 4; r++) {
        float ps = r == 0 ? pool0 : (r == 1 ? pool1 : (r == 2 ? pool2 : pool3));
        float pm = r == 0 ? pmac0 : (r == 1 ? pmac1 : (r == 2 ? pmac2 : pmac3));
        ps += __shfl_xor(ps, 16); ps += __shfl_xor(ps, 32);
        pm += __shfl_xor(pm, 16); pm += __shfl_xor(pm, 32);
        if (quad == 0) {
            atomicAdd(&sum_all[r * 16 + nn], ps);
            atomicAdd(&sum_mac[r * 16 + nn], pm);
        }
    }
}

// ---------- tiny MLP head ----------
__global__ __launch_bounds__(256) void k_final(
    const float* __restrict__ sum_all, const float* __restrict__ sum_mac,
    const float* __restrict__ Wm1, const float* __restrict__ bm1,
    const float* __restrict__ Wm2, const float* __restrict__ bm2,
    const float* __restrict__ Wm3, const float* __restrict__ bm3,
    float* __restrict__ out)
{
    __shared__ float spool[128];
    __shared__ float z1[64];
    __shared__ float z2[32];
    if (threadIdx.x < 64) {
        spool[threadIdx.x]      = sum_mac[threadIdx.x] / (float)N_MACRO;
        spool[64 + threadIdx.x] = sum_all[threadIdx.x] / (float)N_NODES;
    }
    __syncthreads();
    if (threadIdx.x < 64) {
        int j = threadIdx.x;
        float a = bm1[j];
        #pragma unroll 4
        for (int k = 0; k < 128; k++) a += spool[k] * Wm1[k * 64 + j];
        z1[j] = lrelu(a);
    }
    __syncthreads();
    if (threadIdx.x < 32) {
        int j = threadIdx.x;
        float a = bm2[j];
        #pragma unroll 4
        for (int k = 0; k < 64; k++) a += z1[k] * Wm2[k * 32 + j];
        z2[j] = lrelu(a);
    }
    __syncthreads();
    if (threadIdx.x == 0) {
        float a = bm3[0];
        #pragma unroll
        for (int k = 0; k < 32; k++) a += z2[k] * Wm3[k];
        out[0] = a;
    }
}

// ---------- launch ----------
extern "C" void kernel_launch(void* const* d_in, const int* in_sizes, int n_in,
                              void* d_out, int out_size, void* d_ws, size_t ws_size,
                              hipStream_t stream)
{
    const float* x        = (const float*)d_in[0];
    const float* fake_pos = (const float*)d_in[1];
    const int*   edge     = (const int*)d_in[2];
    const float* pinf     = (const float*)d_in[3];
    const int*   macro    = (const int*)d_in[4];
    const float* W1    = (const float*)d_in[5];
    const float* b1    = (const float*)d_in[6];
    const float* Wpin  = (const float*)d_in[7];
    const float* att   = (const float*)d_in[8];
    const float* Wpost = (const float*)d_in[9];
    const float* bpost = (const float*)d_in[10];
    const float* Wm1   = (const float*)d_in[11];
    const float* bm1   = (const float*)d_in[12];
    const float* Wm2   = (const float*)d_in[13];
    const float* bm2   = (const float*)d_in[14];
    const float* Wm3   = (const float*)d_in[15];
    const float* bm3   = (const float*)d_in[16];
    float* out = (float*)d_out;

    float* ws = (float*)d_ws;
    // layout (4-byte units); zero region = [0, 700128)
    float*    ismacro = ws;                         //   200,000
    float*    sum_all = ws + 200000;                //        64
    float*    sum_mac = ws + 200064;                //        64
    int*      mcount  = (int*)(ws + 200128);        //   200,000
    int*      cnt     = (int*)(ws + 400128);        //   300,000
    // end zero region (700,128)
    int*      row_ptr  = (int*)(ws + 700128);       //   300,001
    int*      partials = (int*)(ws + 1000132);      //       300
    float*    va       = ws + 1000432;              //        40
    unsigned short* Wt = (unsigned short*)(ws + 1000472); // 16,384 ushorts (8,192 units)
    int*      rank_n   = (int*)(ws + 1008664);      // 1,000,000
    int*      rank_e   = (int*)(ws + 2008664);      // 1,000,000
    int*      csr_n    = (int*)(ws + 3008664);      // 1,000,000 (node side: he ids)
    int4*     rec      = (int4*)(ws + 4008664);     // 1M x 16B = 4,000,000 units (16B-aligned)
    float*    e_att    = ws + 8008664;              //   100,000
    float*    xn_att   = ws + 8108664;              //   200,000
    unsigned short* h      = (unsigned short*)(ws + 8308664);  // 6.4M ushort (3.2M units)
    unsigned short* e_feat = (unsigned short*)(ws + 11508664); // 6.4M ushort (3.2M units)
    // total: 14,708,664 units ~= 58.8 MB

    const int* nidx = edge;
    const int* hidx = edge + NNZ;

    fill_f32<<<1024, 256, 0, stream>>>(ws, 700128LL, 0.f);
    k_tiny<<<11, 256, 0, stream>>>(macro, ismacro, mcount, W1, b1, att, va, Wpost, Wt);
    k_cnt_h<<<3072, 256, 0, stream>>>(nidx, hidx, cnt, rank_n, rank_e,
                                      x, fake_pos, ismacro, va, h, xn_att);
    k_scan1<<<NB_SCAN, 256, 0, stream>>>(cnt, row_ptr, partials);
    k_scan2<<<1, 512, 0, stream>>>(partials);
    k_scan3<<<NB_SCAN, 256, 0, stream>>>(row_ptr, partials);
    k_scatter<<<2048, 256, 0, stream>>>(nidx, hidx, row_ptr, rank_n, rank_e,
                                        (const float4*)pinf, csr_n, rec);
    k_he_agg<<<2048, 256, 0, stream>>>(row_ptr, rec, W1, Wpin, b1, att, h, e_feat, e_att);
    k_fused<<<2048, 256, 0, stream>>>(row_ptr, csr_n, xn_att, e_att, e_feat, Wt, bpost,
                                      mcount, sum_all, sum_mac);
    k_final<<<1, 256, 0, stream>>>(sum_all, sum_mac, Wm1, bm1, Wm2, bm2, Wm3, bm3, out);
}

// Round 17
// 479.240 us; speedup vs baseline: 1.4128x; 1.4128x over previous
//
#include <hip/hip_runtime.h>
#include <math.h>

#define N_NODES 200000
#define N_HE    100000
#define NNZ     1000000
#define F_RAW   29
#define N_MACRO 512
#define SLOPE   0.1f
#define L_TOTAL (N_NODES + N_HE)   // 300000 combined counters
#define NB_SCAN 293                // ceil(300000/1024)

typedef __attribute__((ext_vector_type(8))) short bf16x8;
typedef __attribute__((ext_vector_type(4))) float f32x4;

__device__ __forceinline__ float lrelu(float v) { return v >= 0.f ? v : SLOPE * v; }
__device__ __forceinline__ float bf2f(unsigned short u) { return __uint_as_float(((unsigned)u) << 16); }
__device__ __forceinline__ unsigned short f2bf(float f) {
    unsigned u = __float_as_uint(f);
    unsigned r = u + 0x7FFFu + ((u >> 16) & 1u);   // RNE
    return (unsigned short)(r >> 16);
}
__device__ __forceinline__ float bflo(unsigned u) { return __uint_as_float(u << 16); }
__device__ __forceinline__ float bfhi(unsigned u) { return __uint_as_float(u & 0xffff0000u); }

// ---------- fill ----------
__global__ __launch_bounds__(256) void fill_f32(float* p, long long n, float v) {
    long long i = (long long)blockIdx.x * blockDim.x + threadIdx.x;
    long long st = (long long)gridDim.x * blockDim.x;
    for (; i < n; i += st) p[i] = v;
}

// ---------- fused pre-pass: va (block 0) + ismacro (blocks 1-2) + count (blocks 3+) ----------
__global__ __launch_bounds__(256) void k_pre(
    const int* __restrict__ mi, float* __restrict__ ismacro, int* __restrict__ mcount,
    const float* __restrict__ W1, const float* __restrict__ b1,
    const float* __restrict__ att, float* __restrict__ va,
    const int* __restrict__ nidx, const int* __restrict__ hidx,
    int* __restrict__ cnt, int* __restrict__ rank_n, int* __restrict__ rank_e)
{
    if (blockIdx.x == 0) {
        int t = threadIdx.x;
        if (t < 32) {
            float a = 0.f;
            for (int c = 0; c < 64; c++) a += W1[t * 64 + c] * att[c];
            va[t] = a;
        } else if (t == 32) {
            float a = 0.f;
            for (int c = 0; c < 64; c++) a += b1[c] * att[c];
            va[32] = a;
        }
    } else if (blockIdx.x <= 2) {
        int i = (blockIdx.x - 1) * 256 + threadIdx.x;
        if (i < N_MACRO) {
            ismacro[mi[i]] = 1.0f;
            atomicAdd(&mcount[mi[i]], 1);
        }
    } else {
        int i = (blockIdx.x - 3) * 256 + threadIdx.x;
        int st = (gridDim.x - 3) * 256;
        for (int p = i; p < NNZ; p += st) {
            rank_n[p] = atomicAdd(&cnt[nidx[p]], 1);
            rank_e[p] = atomicAdd(&cnt[N_NODES + hidx[p]], 1);
        }
    }
}

// ---------- scan of cnt (length L_TOTAL) -> row_ptr ----------
__global__ __launch_bounds__(256) void k_scan1(const int* __restrict__ cnt,
                                               int* __restrict__ row_ptr, int* __restrict__ partials)
{
    __shared__ int sA[256], sB[256];
    const int t = threadIdx.x;
    const int base = blockIdx.x * 1024 + t * 4;
    int v0 = base + 0 < L_TOTAL ? cnt[base + 0] : 0;
    int v1 = base + 1 < L_TOTAL ? cnt[base + 1] : 0;
    int v2 = base + 2 < L_TOTAL ? cnt[base + 2] : 0;
    int v3 = base + 3 < L_TOTAL ? cnt[base + 3] : 0;
    sA[t] = v0 + v1 + v2 + v3;
    __syncthreads();
    int* src = sA; int* dst = sB;
    for (int off = 1; off < 256; off <<= 1) {
        int v = src[t];
        if (t >= off) v += src[t - off];
        dst[t] = v;
        __syncthreads();
        int* tmp = src; src = dst; dst = tmp;
    }
    int excl = t > 0 ? src[t - 1] : 0;
    if (base + 0 < L_TOTAL) row_ptr[base + 0] = excl;
    if (base + 1 < L_TOTAL) row_ptr[base + 1] = excl + v0;
    if (base + 2 < L_TOTAL) row_ptr[base + 2] = excl + v0 + v1;
    if (base + 3 < L_TOTAL) row_ptr[base + 3] = excl + v0 + v1 + v2;
    if (t == 255) partials[blockIdx.x] = src[255];
}

__global__ __launch_bounds__(512) void k_scan2(int* __restrict__ partials)
{
    __shared__ int sA[512], sB[512];
    const int t = threadIdx.x;
    sA[t] = t < NB_SCAN ? partials[t] : 0;
    __syncthreads();
    int* src = sA; int* dst = sB;
    for (int off = 1; off < 512; off <<= 1) {
        int v = src[t];
        if (t >= off) v += src[t - off];
        dst[t] = v;
        __syncthreads();
        int* tmp = src; src = dst; dst = tmp;
    }
    if (t < NB_SCAN) partials[t] = t > 0 ? src[t - 1] : 0;
    if (t == 0) partials[NB_SCAN] = src[511];
}

__global__ __launch_bounds__(256) void k_scan3(int* __restrict__ row_ptr, const int* __restrict__ partials)
{
    const int base = blockIdx.x * 1024 + threadIdx.x * 4;
    int add = partials[blockIdx.x];
    #pragma unroll
    for (int k = 0; k < 4; k++)
        if (base + k < L_TOTAL) row_ptr[base + k] += add;
    if (blockIdx.x == 0 && threadIdx.x == 0) row_ptr[L_TOTAL] = partials[NB_SCAN];
}

// ---------- fused mid-pass: scatter (blocks 0..2047) + h build (blocks 2048..3071) ----------
// scatter: csr_n[slot]=he id; he-side one int4 record {node, pf01, pf23, 0} (single 16B sector).
__global__ __launch_bounds__(256) void k_mid(
    const int* __restrict__ nidx, const int* __restrict__ hidx,
    const int* __restrict__ row_ptr,
    const int* __restrict__ rank_n, const int* __restrict__ rank_e,
    const float4* __restrict__ pf4, int* __restrict__ csr_n, int4* __restrict__ rec,
    const float* __restrict__ x, const float* __restrict__ fp,
    const float* __restrict__ ismacro, const float* __restrict__ va,
    unsigned short* __restrict__ h, float* __restrict__ xn_att)
{
    if (blockIdx.x < 2048) {
        int i = blockIdx.x * 256 + threadIdx.x;
        int st = 2048 * 256;
        for (int p = i; p < NNZ; p += st) {
            int n = nidx[p], e = hidx[p];
            csr_n[row_ptr[n] + rank_n[p]] = e;
            int pe = row_ptr[N_NODES + e] + rank_e[p];  // absolute he slot (>= NNZ)
            float4 q = pf4[p];
            int4 r;
            r.x = n;
            r.y = (int)((unsigned)f2bf(q.x) | ((unsigned)f2bf(q.y) << 16));
            r.z = (int)((unsigned)f2bf(q.z) | ((unsigned)f2bf(q.w) << 16));
            r.w = 0;
            rec[pe - NNZ] = r;
        }
    } else {
        const int lane = threadIdx.x & 63;
        const int half = lane >> 5, k = lane & 31;
        int wid = ((blockIdx.x - 2048) * 256 + threadIdx.x) >> 6;
        int nw = (1024 * 256) >> 6;
        float vak = va[k];
        float c0 = va[32];
        for (int base = wid * 2; base < N_NODES; base += nw * 2) {
            int n = base + half;
            float v;
            if (k < 29)       v = x[(size_t)n * F_RAW + k];
            else if (k == 29) v = fp[2 * n];
            else if (k == 30) v = fp[2 * n + 1];
            else              v = ismacro[n];
            h[(size_t)n * 32 + k] = f2bf(v);
            float r = v * vak;
            #pragma unroll
            for (int o = 16; o > 0; o >>= 1) r += __shfl_xor(r, o, 32);
            if (k == 0) xn_att[n] = r + c0;
        }
    }
}

// ---------- he-side: 8-lane pin groups (8-16 rows in flight), merged rec reads ----------
__global__ __launch_bounds__(256) void k_he_agg(
    const int* __restrict__ row_ptr, const int4* __restrict__ rec,
    const float* __restrict__ W1, const float* __restrict__ Wpin,
    const float* __restrict__ b1, const float* __restrict__ att,
    const unsigned short* __restrict__ h,
    unsigned short* __restrict__ e_feat, float* __restrict__ e_att)
{
    __shared__ float sW1[32 * 64];
    __shared__ float sWp[4 * 64];
    __shared__ float sb1[64];
    for (int i = threadIdx.x; i < 32 * 64; i += 256) sW1[i] = W1[i];
    for (int i = threadIdx.x; i < 4 * 64; i += 256) sWp[i] = Wpin[i];
    if (threadIdx.x < 64) sb1[threadIdx.x] = b1[threadIdx.x];
    __syncthreads();
    const int lane = threadIdx.x & 63;
    const int g  = lane >> 3;    // pin group 0..7
    const int gl = lane & 7;     // channel quad: k = 4gl..4gl+3
    float att2 = att[64 + lane];
    int wid = (blockIdx.x * blockDim.x + threadIdx.x) >> 6;
    int nw = (gridDim.x * blockDim.x) >> 6;
    for (int e = wid; e < N_HE; e += nw) {
        int start = row_ptr[N_NODES + e];
        int deg = row_ptr[N_NODES + e + 1] - start;
        float h0 = 0.f, h1 = 0.f, h2 = 0.f, h3 = 0.f;
        float pa = 0.f, pb = 0.f;
        const int4* rbase = rec + (start - NNZ);
        int t = g;
        for (; t + 8 < deg; t += 16) {
            int4 rA = rbase[t];
            int4 rB = rbase[t + 8];
            ushort4 uA = *(const ushort4*)&h[(size_t)rA.x * 32 + 4 * gl];
            ushort4 uB = *(const ushort4*)&h[(size_t)rB.x * 32 + 4 * gl];
            h0 += bf2f(uA.x) + bf2f(uB.x);
            h1 += bf2f(uA.y) + bf2f(uB.y);
            h2 += bf2f(uA.z) + bf2f(uB.z);
            h3 += bf2f(uA.w) + bf2f(uB.w);
            unsigned pyA = (gl == 0) ? (unsigned)rA.y : ((gl == 1) ? (unsigned)rA.z : 0u);
            unsigned pyB = (gl == 0) ? (unsigned)rB.y : ((gl == 1) ? (unsigned)rB.z : 0u);
            pa += bflo(pyA) + bflo(pyB);
            pb += bfhi(pyA) + bfhi(pyB);
        }
        if (t < deg) {
            int4 r = rbase[t];
            ushort4 u = *(const ushort4*)&h[(size_t)r.x * 32 + 4 * gl];
            h0 += bf2f(u.x); h1 += bf2f(u.y); h2 += bf2f(u.z); h3 += bf2f(u.w);
            unsigned py = (gl == 0) ? (unsigned)r.y : ((gl == 1) ? (unsigned)r.z : 0u);
            pa += bflo(py); pb += bfhi(py);
        }
        // combine the 8 pin groups (lane bits 3..5)
        #pragma unroll
        for (int o = 8; o <= 32; o <<= 1) {
            h0 += __shfl_xor(h0, o); h1 += __shfl_xor(h1, o);
            h2 += __shfl_xor(h2, o); h3 += __shfl_xor(h3, o);
            pa += __shfl_xor(pa, o); pb += __shfl_xor(pb, o);
        }
        float p0 = __shfl(pa, 0, 64), p1 = __shfl(pb, 0, 64);
        float p2 = __shfl(pa, 1, 64), p3 = __shfl(pb, 1, 64);
        float acc = (float)deg * sb1[lane]
                  + p0 * sWp[lane] + p1 * sWp[64 + lane]
                  + p2 * sWp[128 + lane] + p3 * sWp[192 + lane];
        #pragma unroll
        for (int kk = 0; kk < 8; kk++) {
            float a0 = __shfl(h0, kk, 64), a1 = __shfl(h1, kk, 64);
            float a2 = __shfl(h2, kk, 64), a3 = __shfl(h3, kk, 64);
            acc += a0 * sW1[(4 * kk + 0) * 64 + lane] + a1 * sW1[(4 * kk + 1) * 64 + lane]
                 + a2 * sW1[(4 * kk + 2) * 64 + lane] + a3 * sW1[(4 * kk + 3) * 64 + lane];
        }
        float d = (float)(deg > 0 ? deg : 1);
        float v = acc / d;
        e_feat[(size_t)e * 64 + lane] = f2bf(v);
        float r = v * att2;
        #pragma unroll
        for (int o = 32; o > 0; o >>= 1) r += __shfl_down(r, o, 64);
        if (lane == 0) e_att[e] = r;
    }
}

// ---------- fused softmax+PNA (half-wave pin split) + MFMA post-GEMM + pools ----------
// (R11/R12 structure - best measured at ~144-150 us; VGPR 40, no spill)
__global__ __launch_bounds__(256, 4) void k_fused(
    const int* __restrict__ row_ptr, const int* __restrict__ csr,
    const float* __restrict__ xn_att, const float* __restrict__ e_att,
    const unsigned short* __restrict__ e_feat,
    const float* __restrict__ Wpost, const float* __restrict__ bpost,
    const int* __restrict__ mcount,
    float* __restrict__ sum_all, float* __restrict__ sum_mac)
{
    __shared__ __align__(16) unsigned short scat[16 * 264];   // 8448 B
    const int lane = threadIdx.x & 63;
    const int wave = threadIdx.x >> 6;
    const int half = lane >> 5;     // pin parity
    const int c2   = lane & 31;     // channel pair: channels 2c2, 2c2+1
    const int quad = lane >> 4;     // phase B
    const int nn   = lane & 15;     // phase B
    bf16x8 wfrag[8];
    #pragma unroll
    for (int s = 0; s < 8; s++) {
        bf16x8 w;
        #pragma unroll
        for (int j = 0; j < 8; j++)
            w[j] = (short)f2bf(Wpost[(size_t)(32 * s + quad * 8 + j) * 64 + wave * 16 + nn]);
        wfrag[s] = w;
    }
    float bias = bpost[wave * 16 + nn];
    float pool = 0.f, pmac = 0.f;
    const int nbatches = N_NODES / 16;  // 12500
    for (int b = blockIdx.x; b < nbatches; b += gridDim.x) {
        const int base = b * 16;
        __syncthreads();
        for (int i = 0; i < 4; i++) {
            int j = wave * 4 + i;
            int n = base + j;
            int start = row_ptr[n];
            int deg = row_ptr[n + 1] - start;
            float xn = xn_att[n];
            float sw = 0.f;
            float sx = 0.f, sy = 0.f, qx = 0.f, qy = 0.f;
            float mxx = -INFINITY, mxy = -INFINITY, mnx = INFINITY, mny = INFINITY;
            int t = half;
            for (; t + 2 < deg; t += 4) {
                int e0 = csr[start + t];
                int e1 = csr[start + t + 2];
                float w0 = __expf(lrelu(xn + e_att[e0]));
                float w1 = __expf(lrelu(xn + e_att[e1]));
                unsigned u0 = ((const unsigned*)&e_feat[(size_t)e0 * 64])[c2];
                unsigned u1 = ((const unsigned*)&e_feat[(size_t)e1 * 64])[c2];
                float v0x = bflo(u0) * w0, v0y = bfhi(u0) * w0;
                float v1x = bflo(u1) * w1, v1y = bfhi(u1) * w1;
                sw += w0 + w1;
                sx += v0x + v1x; sy += v0y + v1y;
                qx += v0x * v0x + v1x * v1x; qy += v0y * v0y + v1y * v1y;
                mxx = fmaxf(mxx, fmaxf(v0x, v1x)); mxy = fmaxf(mxy, fmaxf(v0y, v1y));
                mnx = fminf(mnx, fminf(v0x, v1x)); mny = fminf(mny, fminf(v0y, v1y));
            }
            for (; t < deg; t += 2) {
                int e = csr[start + t];
                float w = __expf(lrelu(xn + e_att[e]));
                unsigned u = ((const unsigned*)&e_feat[(size_t)e * 64])[c2];
                float vx = bflo(u) * w, vy = bfhi(u) * w;
                sw += w; sx += vx; sy += vy; qx += vx * vx; qy += vy * vy;
                mxx = fmaxf(mxx, vx); mxy = fmaxf(mxy, vy);
                mnx = fminf(mnx, vx); mny = fminf(mny, vy);
            }
            sw  += __shfl_xor(sw, 32);
            sx  += __shfl_xor(sx, 32);  sy += __shfl_xor(sy, 32);
            qx  += __shfl_xor(qx, 32);  qy += __shfl_xor(qy, 32);
            mxx = fmaxf(mxx, __shfl_xor(mxx, 32)); mxy = fmaxf(mxy, __shfl_xor(mxy, 32));
            mnx = fminf(mnx, __shfl_xor(mnx, 32)); mny = fminf(mny, __shfl_xor(mny, 32));
            float invD = 1.f / (sw + 1e-16f);
            float dc = (float)(deg > 0 ? deg : 1);
            float meanx = sx * invD / dc, meany = sy * invD / dc;
            float sqmx = qx * invD * invD / dc, sqmy = qy * invD * invD / dc;
            float stdx = sqrtf(fmaxf(sqmx - meanx * meanx, 0.f) + 1e-12f);
            float stdy = sqrtf(fmaxf(sqmy - meany * meany, 0.f) + 1e-12f);
            ushort2* row = (ushort2*)&scat[j * 264];
            if (half == 0) {
                ushort2 a; a.x = f2bf(meanx); a.y = f2bf(meany);
                row[c2] = a;
                ushort2 bmax; bmax.x = f2bf(deg > 0 ? mxx * invD : 0.f);
                bmax.y = f2bf(deg > 0 ? mxy * invD : 0.f);
                row[32 + c2] = bmax;
            } else {
                ushort2 bmin; bmin.x = f2bf(deg > 0 ? mnx * invD : 0.f);
                bmin.y = f2bf(deg > 0 ? mny * invD : 0.f);
                row[64 + c2] = bmin;
                ushort2 bstd; bstd.x = f2bf(stdx); bstd.y = f2bf(stdy);
                row[96 + c2] = bstd;
            }
        }
        __syncthreads();
        f32x4 acc = {0.f, 0.f, 0.f, 0.f};
        #pragma unroll
        for (int s = 0; s < 8; s++) {
            bf16x8 a = *(const bf16x8*)&scat[nn * 264 + 32 * s + quad * 8];
            acc = __builtin_amdgcn_mfma_f32_16x16x32_bf16(a, wfrag[s], acc, 0, 0, 0);
        }
        int4 mc4 = *(const int4*)&mcount[base + 4 * quad];
        float h0 = lrelu(acc[0] + bias);
        float h1 = lrelu(acc[1] + bias);
        float h2 = lrelu(acc[2] + bias);
        float h3 = lrelu(acc[3] + bias);
        pool += h0 + h1 + h2 + h3;
        pmac += (float)mc4.x * h0 + (float)mc4.y * h1 + (float)mc4.z * h2 + (float)mc4.w * h3;
    }
    pool += __shfl_xor(pool, 16); pool += __shfl_xor(pool, 32);
    pmac += __shfl_xor(pmac, 16); pmac += __shfl_xor(pmac, 32);
    if (quad == 0) {
        atomicAdd(&sum_all[wave * 16 + nn], pool);
        atomicAdd(&sum_mac[wave * 16 + nn], pmac);
    }
}

// ---------- tiny MLP head ----------
__global__ __launch_bounds__(256) void k_final(
    const float* __restrict__ sum_all, const float* __restrict__ sum_mac,
    const float* __restrict__ Wm1, const float* __restrict__ bm1,
    const float* __restrict__ Wm2, const float* __restrict__ bm2,
    const float* __restrict__ Wm3, const float* __restrict__ bm3,
    float* __restrict__ out)
{
    __shared__ float spool[128];
    __shared__ float z1[64];
    __shared__ float z2[32];
    if (threadIdx.x < 64) {
        spool[threadIdx.x]      = sum_mac[threadIdx.x] / (float)N_MACRO;
        spool[64 + threadIdx.x] = sum_all[threadIdx.x] / (float)N_NODES;
    }
    __syncthreads();
    if (threadIdx.x < 64) {
        int j = threadIdx.x;
        float a = bm1[j];
        #pragma unroll 4
        for (int k = 0; k < 128; k++) a += spool[k] * Wm1[k * 64 + j];
        z1[j] = lrelu(a);
    }
    __syncthreads();
    if (threadIdx.x < 32) {
        int j = threadIdx.x;
        float a = bm2[j];
        #pragma unroll 4
        for (int k = 0; k < 64; k++) a += z1[k] * Wm2[k * 32 + j];
        z2[j] = lrelu(a);
    }
    __syncthreads();
    if (threadIdx.x == 0) {
        float a = bm3[0];
        #pragma unroll
        for (int k = 0; k < 32; k++) a += z2[k] * Wm3[k];
        out[0] = a;
    }
}

// ---------- launch ----------
extern "C" void kernel_launch(void* const* d_in, const int* in_sizes, int n_in,
                              void* d_out, int out_size, void* d_ws, size_t ws_size,
                              hipStream_t stream)
{
    const float* x        = (const float*)d_in[0];
    const float* fake_pos = (const float*)d_in[1];
    const int*   edge     = (const int*)d_in[2];
    const float* pinf     = (const float*)d_in[3];
    const int*   macro    = (const int*)d_in[4];
    const float* W1    = (const float*)d_in[5];
    const float* b1    = (const float*)d_in[6];
    const float* Wpin  = (const float*)d_in[7];
    const float* att   = (const float*)d_in[8];
    const float* Wpost = (const float*)d_in[9];
    const float* bpost = (const float*)d_in[10];
    const float* Wm1   = (const float*)d_in[11];
    const float* bm1   = (const float*)d_in[12];
    const float* Wm2   = (const float*)d_in[13];
    const float* bm2   = (const float*)d_in[14];
    const float* Wm3   = (const float*)d_in[15];
    const float* bm3   = (const float*)d_in[16];
    float* out = (float*)d_out;

    float* ws = (float*)d_ws;
    // layout (4-byte units); zero region = [0, 700128)
    float*    ismacro = ws;                         //   200,000
    float*    sum_all = ws + 200000;                //        64
    float*    sum_mac = ws + 200064;                //        64
    int*      mcount  = (int*)(ws + 200128);        //   200,000
    int*      cnt     = (int*)(ws + 400128);        //   300,000
    // end zero region (700,128)
    int*      row_ptr  = (int*)(ws + 700128);       //   300,001
    int*      partials = (int*)(ws + 1000132);      //       300
    float*    va       = ws + 1000432;              //        40
    int*      rank_n   = (int*)(ws + 1000472);      // 1,000,000
    int*      rank_e   = (int*)(ws + 2000472);      // 1,000,000
    int*      csr_n    = (int*)(ws + 3000472);      // 1,000,000 (node side: he ids)
    int4*     rec      = (int4*)(ws + 4000472);     // 1M x 16B = 4,000,000 units (16B-aligned)
    float*    e_att    = ws + 8000472;              //   100,000
    float*    xn_att   = ws + 8100472;              //   200,000
    unsigned short* h      = (unsigned short*)(ws + 8300472);  // 6.4M ushort (3.2M units)
    unsigned short* e_feat = (unsigned short*)(ws + 11500472); // 6.4M ushort (3.2M units)
    // total: 14,700,472 units ~= 58.8 MB

    const int* nidx = edge;
    const int* hidx = edge + NNZ;

    fill_f32<<<1024, 256, 0, stream>>>(ws, 700128LL, 0.f);
    k_pre<<<2051, 256, 0, stream>>>(macro, ismacro, mcount, W1, b1, att, va,
                                    nidx, hidx, cnt, rank_n, rank_e);
    k_scan1<<<NB_SCAN, 256, 0, stream>>>(cnt, row_ptr, partials);
    k_scan2<<<1, 512, 0, stream>>>(partials);
    k_scan3<<<NB_SCAN, 256, 0, stream>>>(row_ptr, partials);
    k_mid<<<3072, 256, 0, stream>>>(nidx, hidx, row_ptr, rank_n, rank_e,
                                    (const float4*)pinf, csr_n, rec,
                                    x, fake_pos, ismacro, va, h, xn_att);
    k_he_agg<<<2048, 256, 0, stream>>>(row_ptr, rec, W1, Wpin, b1, att, h, e_feat, e_att);
    k_fused<<<4096, 256, 0, stream>>>(row_ptr, csr_n, xn_att, e_att, e_feat, Wpost, bpost,
                                      mcount, sum_all, sum_mac);
    k_final<<<1, 256, 0, stream>>>(sum_all, sum_mac, Wm1, bm1, Wm2, bm2, Wm3, bm3, out);
}